// Round 1
// baseline (697.956 us; speedup 1.0000x reference)
//
#include <hip/hip_runtime.h>
#include <math.h>

#define PI_F 3.14159265358979323846f

constexpr int TB = 64;   // batch rows per block

// Swizzled LDS index for the transposed activation tile xt[k][r], k,r in [0,256)x[0,64).
// Element-granularity XOR keeps all access patterns <=2-way bank conflicts:
//  - staging writes (k varies across lanes, r fixed)
//  - k-loop reads (k fixed, 8 r-values broadcast)
//  - transposed layer-output writes (c=k varies with lane cg, r with rg)
__device__ __forceinline__ int xswz(int k, int r) {
    return (k << 6) + (r ^ (k & 31) ^ (k >> 5));
}

__device__ __forceinline__ float apply_act(int a, float x) {
    switch (a) {
        case 2:  return x > 0.0f ? 1.0f : 0.0f;
        case 3:  return sinf(PI_F * x);
        case 4:  return expf(-0.5f * x * x);
        case 5:  return tanhf(x);
        case 6:  return 0.5f * (tanhf(0.5f * x) + 1.0f);
        case 7:  return -x;
        case 8:  return fabsf(x);
        case 9:  return fmaxf(0.0f, x);
        case 10: return cosf(PI_F * x);
        case 11: return x * x;
        default: return x;  // ids 0,1 -> identity
    }
}

// One dense layer: reads xt (transposed, swizzled), K=256 always.
// BIAS: W has 257 rows, row 0 is the bias (input had a leading ones column).
// Non-LAST: writes activated output transposed back into xt (it becomes next layer's input).
// LAST: writes activated output to global memory.
template<int N, int RPT, int CPT, bool BIAS, bool LAST>
__device__ __forceinline__ void layer(const float* __restrict__ W,
                                      const int* __restrict__ act,
                                      float* xt, float* __restrict__ outg,
                                      int row0, int tid) {
    constexpr int CG = N / CPT;          // col groups
    const int cg = tid % CG;
    const int rg = tid / CG;
    const int c0 = cg * CPT;
    const int r0 = rg * RPT;

    float acc[RPT][CPT];
    #pragma unroll
    for (int j = 0; j < CPT; ++j) {
        const float b = BIAS ? W[c0 + j] : 0.0f;
        #pragma unroll
        for (int i = 0; i < RPT; ++i) acc[i][j] = b;
    }
    const float* Wk = W + (BIAS ? N : 0);

    #pragma unroll 2
    for (int k = 0; k < 256; ++k) {
        float xv[RPT];
        #pragma unroll
        for (int i = 0; i < RPT; ++i) xv[i] = xt[xswz(k, r0 + i)];
        float wv[CPT];
        #pragma unroll
        for (int j = 0; j < CPT; j += 4) {
            const float4 w4 = *reinterpret_cast<const float4*>(&Wk[k * N + c0 + j]);
            wv[j] = w4.x; wv[j + 1] = w4.y; wv[j + 2] = w4.z; wv[j + 3] = w4.w;
        }
        #pragma unroll
        for (int i = 0; i < RPT; ++i)
            #pragma unroll
            for (int j = 0; j < CPT; ++j)
                acc[i][j] = fmaf(xv[i], wv[j], acc[i][j]);
    }

    // per-node activation (id is per output column)
    #pragma unroll
    for (int j = 0; j < CPT; ++j) {
        const int a = act[c0 + j];
        #pragma unroll
        for (int i = 0; i < RPT; ++i) acc[i][j] = apply_act(a, acc[i][j]);
    }

    __syncthreads();  // everyone done READING xt before we overwrite it
    if (LAST) {
        #pragma unroll
        for (int i = 0; i < RPT; ++i) {
            #pragma unroll
            for (int j = 0; j < CPT; j += 4) {
                const float4 v = make_float4(acc[i][j], acc[i][j + 1],
                                             acc[i][j + 2], acc[i][j + 3]);
                *reinterpret_cast<float4*>(&outg[(size_t)(row0 + r0 + i) * N + c0 + j]) = v;
            }
        }
    } else {
        #pragma unroll
        for (int j = 0; j < CPT; ++j)
            #pragma unroll
            for (int i = 0; i < RPT; ++i)
                xt[xswz(c0 + j, r0 + i)] = acc[i][j];
        __syncthreads();  // writes visible before next layer reads
    }
}

__global__ __launch_bounds__(256, 2)
void wann_fused(const float* __restrict__ x,
                const float* __restrict__ W0, const float* __restrict__ W1,
                const float* __restrict__ W2,
                const int* __restrict__ a1, const int* __restrict__ a2,
                const int* __restrict__ a3,
                float* __restrict__ out) {
    __shared__ float xt[256 * 64];  // exactly 64 KiB -> 2 blocks/CU
    const int tid = threadIdx.x;
    const int row0 = blockIdx.x * TB;

    // stage x[row0:row0+64, 0:256] transposed into xt[k][r] (coalesced global reads)
    {
        const float4* xv4 = reinterpret_cast<const float4*>(x + (size_t)row0 * 256);
        #pragma unroll
        for (int p = 0; p < 16; ++p) {
            const int f = p * 256 + tid;       // float4 index within the tile
            const int r = f >> 6;              // 64 float4 per row
            const int k4 = (f & 63) << 2;
            const float4 v = xv4[f];
            xt[xswz(k4 + 0, r)] = v.x;
            xt[xswz(k4 + 1, r)] = v.y;
            xt[xswz(k4 + 2, r)] = v.z;
            xt[xswz(k4 + 3, r)] = v.w;
        }
    }
    __syncthreads();

    layer<256, 8, 8, true,  false>(W0, a1, xt, nullptr, row0, tid);
    layer<256, 8, 8, false, false>(W1, a2, xt, nullptr, row0, tid);
    layer<128, 4, 8, false, true >(W2, a3, xt, out,     row0, tid);
}

extern "C" void kernel_launch(void* const* d_in, const int* in_sizes, int n_in,
                              void* d_out, int out_size, void* d_ws, size_t ws_size,
                              hipStream_t stream) {
    const float* x  = (const float*)d_in[0];
    const float* W0 = (const float*)d_in[1];   // [257, 256], row 0 = bias
    const float* W1 = (const float*)d_in[2];   // [256, 256]
    const float* W2 = (const float*)d_in[3];   // [256, 128]
    const int*   a1 = (const int*)d_in[4];
    const int*   a2 = (const int*)d_in[5];
    const int*   a3 = (const int*)d_in[6];
    float* out = (float*)d_out;                // [B, 128] fp32

    const int B = in_sizes[0] / 256;           // 65536
    const int nblocks = B / TB;                // 1024
    hipLaunchKernelGGL(wann_fused, dim3(nblocks), dim3(256), 0, stream,
                       x, W0, W1, W2, a1, a2, a3, out);
}

// Round 2
// 508.363 us; speedup vs baseline: 1.3729x; 1.3729x over previous
//
#include <hip/hip_runtime.h>
#include <hip/hip_bf16.h>
#include <math.h>

#define PI_F 3.14159265358979323846f

typedef __attribute__((ext_vector_type(8)))  short short8;   // 8 bf16 (4 VGPRs) MFMA operand
typedef __attribute__((ext_vector_type(16))) float f32x16;   // 32x32 MFMA accumulator

constexpr int TB = 64;          // batch rows per block
constexpr int PLANE = 32768;    // one LDS split-plane: 64 rows * 256 k * 2B
// LDS addressing for A-split planes, layout [row][k] bf16, row stride 512B.
// XOR swizzle (row&7)<<4 spreads the stride-512B column reads over 8 16B slots.

__device__ __forceinline__ float bf16_rne(float x) {
    unsigned int u = __float_as_uint(x);
    unsigned int r = (u + 0x7fffu + ((u >> 16) & 1u)) & 0xffff0000u;
    return __uint_as_float(r);
}
// exact 3-term split: x == h + m + l + O(2^-24 |x|)
__device__ __forceinline__ void split3(float x, unsigned short& h, unsigned short& m, unsigned short& l) {
    float hf = bf16_rne(x);
    float r1 = x - hf;
    float mf = bf16_rne(r1);
    float r2 = r1 - mf;
    float lf = bf16_rne(r2);
    h = (unsigned short)(__float_as_uint(hf) >> 16);
    m = (unsigned short)(__float_as_uint(mf) >> 16);
    l = (unsigned short)(__float_as_uint(lf) >> 16);
}

__device__ __forceinline__ float apply_act(int a, float x) {
    switch (a) {
        case 2:  return x > 0.0f ? 1.0f : 0.0f;
        case 3:  return sinf(PI_F * x);
        case 4:  return expf(-0.5f * x * x);
        case 5:  return tanhf(x);
        case 6:  return 0.5f * (tanhf(0.5f * x) + 1.0f);
        case 7:  return -x;
        case 8:  return fabsf(x);
        case 9:  return fmaxf(0.0f, x);
        case 10: return cosf(PI_F * x);
        case 11: return x * x;
        default: return x;
    }
}

// ---------------- weight pre-pack ----------------
// ws layout: fragment-linear bf16. Fragment group g covers (layer, ktile t, ctile c).
//   g: L0 -> t*8+c (128), L1 -> 128 + t*8+c (128), L2 -> 256 + t*4+c (64).
// For group g, split s, lane l, elem i: ws[((g*3+s)*64 + l)*8 + i] =
//   split_s( W[k = t*16 + (l>>5)*8 + i][col = c*32 + (l&31)] )  (+1 row offset for W0 bias row)
__global__ void pack_w(const float* __restrict__ W0, const float* __restrict__ W1,
                       const float* __restrict__ W2, unsigned short* __restrict__ ws) {
    const int g = blockIdx.x;        // 0..319
    const int lane = threadIdx.x;    // 0..63
    const int hi = lane >> 5, ln31 = lane & 31;
    const float* W; int t, c, ldw, rowoff;
    if (g < 128)      { W = W0; t = g >> 3;        c = g & 7;        ldw = 256; rowoff = 1; }
    else if (g < 256) { W = W1; t = (g-128) >> 3;  c = (g-128) & 7;  ldw = 256; rowoff = 0; }
    else              { W = W2; t = (g-256) >> 2;  c = (g-256) & 3;  ldw = 128; rowoff = 0; }
    const int col = c * 32 + ln31;
    unsigned short hb[8], mb[8], lb[8];
    #pragma unroll
    for (int i = 0; i < 8; ++i) {
        const int k = t * 16 + hi * 8 + i;
        split3(W[(size_t)(rowoff + k) * ldw + col], hb[i], mb[i], lb[i]);
    }
    size_t base = ((size_t)(g * 3 + 0) * 64 + lane) * 8;
    #pragma unroll
    for (int i = 0; i < 8; ++i) ws[base + i] = hb[i];
    base += 64 * 8;
    #pragma unroll
    for (int i = 0; i < 8; ++i) ws[base + i] = mb[i];
    base += 64 * 8;
    #pragma unroll
    for (int i = 0; i < 8; ++i) ws[base + i] = lb[i];
}

// ---------------- fused main kernel ----------------
// mfma_f32_32x32x16_bf16 operand layouts (A row / B col indexed by lane&31, k by (lane>>5)*8+i;
// D: col=lane&31, row=(reg&3)+8*(reg>>2)+4*(lane>>5) — HW-verified mapping).
template<int NC_TOT, int CPW>
__device__ __forceinline__ void gemm_layer(const short8* __restrict__ wsL, const char* smem,
                                           f32x16* acc, int wid, int lane) {
    const int hi = lane >> 5, ln31 = lane & 31;
    const int wr = wid >> 2, wc = wid & 3;
    const int row = wr * 32 + ln31;
    const int abase = row * 512;
    const int swzm = (row & 7) << 4;
    const int c0 = wc * CPW;
    #pragma unroll 2
    for (int t = 0; t < 16; ++t) {
        const int koff = ((t * 32 + hi * 16) ^ swzm) + abase;
        short8 ah = *(const short8*)(smem + 0 * PLANE + koff);
        short8 am = *(const short8*)(smem + 1 * PLANE + koff);
        short8 al = *(const short8*)(smem + 2 * PLANE + koff);
        #pragma unroll
        for (int c = 0; c < CPW; ++c) {
            const short8* bp = wsL + ((size_t)(t * NC_TOT + c0 + c) * 3) * 64 + lane;
            short8 bh = bp[0];
            short8 bm = bp[64];
            short8 bl = bp[128];
            acc[c] = __builtin_amdgcn_mfma_f32_32x32x16_bf16(ah, bh, acc[c], 0, 0, 0);
            acc[c] = __builtin_amdgcn_mfma_f32_32x32x16_bf16(ah, bm, acc[c], 0, 0, 0);
            acc[c] = __builtin_amdgcn_mfma_f32_32x32x16_bf16(am, bh, acc[c], 0, 0, 0);
            acc[c] = __builtin_amdgcn_mfma_f32_32x32x16_bf16(ah, bl, acc[c], 0, 0, 0);
            acc[c] = __builtin_amdgcn_mfma_f32_32x32x16_bf16(am, bm, acc[c], 0, 0, 0);
            acc[c] = __builtin_amdgcn_mfma_f32_32x32x16_bf16(al, bh, acc[c], 0, 0, 0);
        }
    }
}

// activation + re-split + write back into the (same) LDS planes as next layer's A
template<int CPW>
__device__ __forceinline__ void act_to_lds(f32x16* acc, const int* __restrict__ act,
                                           char* smem, int wid, int lane) {
    const int hi = lane >> 5, ln31 = lane & 31;
    const int wr = wid >> 2, wc = wid & 3;
    __syncthreads();   // everyone done reading previous A
    #pragma unroll
    for (int c = 0; c < CPW; ++c) {
        const int col = wc * (CPW * 32) + c * 32 + ln31;
        const int aid = act[col];
        const int kbyte = 2 * col;
        #pragma unroll
        for (int r = 0; r < 16; ++r) {
            const float v = apply_act(aid, acc[c][r]);
            const int row = wr * 32 + (r & 3) + 8 * (r >> 2) + 4 * hi;
            const int addr = row * 512 + (kbyte ^ ((row & 7) << 4));
            unsigned short h, m, l;
            split3(v, h, m, l);
            *(unsigned short*)(smem + 0 * PLANE + addr) = h;
            *(unsigned short*)(smem + 1 * PLANE + addr) = m;
            *(unsigned short*)(smem + 2 * PLANE + addr) = l;
        }
    }
    __syncthreads();
}

__global__ __launch_bounds__(512, 2)
void wann_mfma(const float* __restrict__ x,
               const float* __restrict__ W0,
               const unsigned short* __restrict__ ws,
               const int* __restrict__ a1, const int* __restrict__ a2,
               const int* __restrict__ a3,
               float* __restrict__ out) {
    extern __shared__ char smem[];           // 3 planes x 32 KiB
    const int tid = threadIdx.x;
    const int lane = tid & 63;
    const int wid = tid >> 6;
    const int ln31 = lane & 31;
    const int hi = lane >> 5;
    const int wr = wid >> 2, wc = wid & 3;
    const int row0 = blockIdx.x * TB;

    // ---- stage x: global float4 -> split3 -> LDS planes ----
    {
        const float4* xv = (const float4*)(x + (size_t)row0 * 256);
        #pragma unroll
        for (int p = 0; p < 8; ++p) {
            const int f = p * 512 + tid;
            const int r = f >> 6;            // row 0..63
            const int swz = (r & 7) << 4;
            const int kb0 = (f & 63) * 8;    // byte offset of first of 4 bf16 pairs
            const float4 v = xv[f];
            const float vv[4] = {v.x, v.y, v.z, v.w};
            #pragma unroll
            for (int e = 0; e < 4; ++e) {
                unsigned short h, m, l;
                split3(vv[e], h, m, l);
                const int addr = r * 512 + ((kb0 + 2 * e) ^ swz);
                *(unsigned short*)(smem + 0 * PLANE + addr) = h;
                *(unsigned short*)(smem + 1 * PLANE + addr) = m;
                *(unsigned short*)(smem + 2 * PLANE + addr) = l;
            }
        }
    }
    __syncthreads();

    const short8* wsv = (const short8*)ws;
    const short8* wsL0 = wsv;
    const short8* wsL1 = wsv + (size_t)128 * 3 * 64;
    const short8* wsL2 = wsv + (size_t)256 * 3 * 64;

    f32x16 acc[2];

    // ---- layer 1: bias from W0 row 0 ----
    {
        #pragma unroll
        for (int c = 0; c < 2; ++c) {
            const float b = W0[wc * 64 + c * 32 + ln31];
            #pragma unroll
            for (int r = 0; r < 16; ++r) acc[c][r] = b;
        }
        gemm_layer<8, 2>(wsL0, smem, acc, wid, lane);
        act_to_lds<2>(acc, a1, smem, wid, lane);
    }

    // ---- layer 2 ----
    {
        #pragma unroll
        for (int c = 0; c < 2; ++c)
            #pragma unroll
            for (int r = 0; r < 16; ++r) acc[c][r] = 0.0f;
        gemm_layer<8, 2>(wsL1, smem, acc, wid, lane);
        act_to_lds<2>(acc, a2, smem, wid, lane);
    }

    // ---- layer 3: 128 cols, 1 ctile/wave, write out ----
    {
        #pragma unroll
        for (int r = 0; r < 16; ++r) acc[0][r] = 0.0f;
        gemm_layer<4, 1>(wsL2, smem, acc, wid, lane);
        const int col = wc * 32 + ln31;
        const int aid = a3[col];
        #pragma unroll
        for (int r = 0; r < 16; ++r) {
            const float v = apply_act(aid, acc[0][r]);
            const int row = wr * 32 + (r & 3) + 8 * (r >> 2) + 4 * hi;
            out[(size_t)(row0 + row) * 128 + col] = v;
        }
    }
}

extern "C" void kernel_launch(void* const* d_in, const int* in_sizes, int n_in,
                              void* d_out, int out_size, void* d_ws, size_t ws_size,
                              hipStream_t stream) {
    const float* x  = (const float*)d_in[0];
    const float* W0 = (const float*)d_in[1];   // [257,256], row 0 = bias
    const float* W1 = (const float*)d_in[2];   // [256,256]
    const float* W2 = (const float*)d_in[3];   // [256,128]
    const int*   a1 = (const int*)d_in[4];
    const int*   a2 = (const int*)d_in[5];
    const int*   a3 = (const int*)d_in[6];
    float* out = (float*)d_out;

    unsigned short* ws = (unsigned short*)d_ws;   // 983040 B of packed bf16 fragments

    static bool attr_set = false;  // idempotent host-side attribute; harmless under capture
    hipFuncSetAttribute(reinterpret_cast<const void*>(wann_mfma),
                        hipFuncAttributeMaxDynamicSharedMemorySize, 3 * PLANE);

    hipLaunchKernelGGL(pack_w, dim3(320), dim3(64), 0, stream, W0, W1, W2, ws);

    const int B = in_sizes[0] / 256;
    hipLaunchKernelGGL(wann_mfma, dim3(B / TB), dim3(512), 3 * PLANE, stream,
                       x, W0, ws, a1, a2, a3, out);
}

// Round 3
// 253.567 us; speedup vs baseline: 2.7525x; 2.0048x over previous
//
#include <hip/hip_runtime.h>
#include <hip/hip_bf16.h>
#include <math.h>

typedef __attribute__((ext_vector_type(8)))  short short8;   // 8 bf16 (4 VGPRs) MFMA operand
typedef __attribute__((ext_vector_type(16))) float f32x16;   // 32x32 MFMA accumulator

constexpr int TB = 64;          // batch rows per block
constexpr int PLANE = 32768;    // one LDS split-plane: 64 rows * 256 k * 2B, row stride 512B
// XOR swizzle (row&7)<<4 spreads the stride-512B column accesses across 8 16B slots.

// ---- fast HW transcendentals ----
__device__ __forceinline__ float vexp2f(float x) {   // 2^x
    float r; asm("v_exp_f32 %0, %1" : "=v"(r) : "v"(x)); return r;
}

__device__ __forceinline__ unsigned int bf16_rne_bits(float x) {
    unsigned int u = __float_as_uint(x);
    return (u + 0x7fffu + ((u >> 16) & 1u)) & 0xffff0000u;
}
// 3-term split: x = h + m + l + O(2^-24 |x|)   (l truncated, not rounded)
__device__ __forceinline__ void split3(float x, unsigned short& h, unsigned short& m, unsigned short& l) {
    const unsigned int hb = bf16_rne_bits(x);
    const float r1 = x - __uint_as_float(hb);
    const unsigned int mb = bf16_rne_bits(r1);
    const float r2 = r1 - __uint_as_float(mb);
    h = (unsigned short)(hb >> 16);
    m = (unsigned short)(mb >> 16);
    l = (unsigned short)(__float_as_uint(r2) >> 16);
}

// Branchless per-node activation. a is per-lane; all candidates are cheap HW ops.
__device__ __forceinline__ float apply_act(int a, float x) {
    const float x2 = x * x;
    const float r  = __builtin_amdgcn_fractf(0.5f * x);       // revolutions for sin/cos(pi*x)
    const float sn = __builtin_amdgcn_sinf(r);                // sin(2*pi*r) = sin(pi*x)
    const float cs = __builtin_amdgcn_cosf(r);                // cos(pi*x)
    const float eg = vexp2f(x2 * -0.72134752044448169f);      // exp(-x^2/2)
    const float th = 1.0f - 2.0f * __builtin_amdgcn_rcpf(vexp2f(x * 2.8853900817779268f) + 1.0f); // tanh
    const float sg = __builtin_amdgcn_rcpf(1.0f + vexp2f(x * -1.4426950408889634f));              // sigmoid
    float v = x;
    v = (a == 2)  ? (x > 0.0f ? 1.0f : 0.0f) : v;
    v = (a == 3)  ? sn : v;
    v = (a == 4)  ? eg : v;
    v = (a == 5)  ? th : v;
    v = (a == 6)  ? sg : v;
    v = (a == 7)  ? -x : v;
    v = (a == 8)  ? fabsf(x) : v;
    v = (a == 9)  ? fmaxf(0.0f, x) : v;
    v = (a == 10) ? cs : v;
    v = (a == 11) ? x2 : v;
    return v;
}

// ---------------- weight pre-pack (unchanged layout from round 2) ----------------
// ws: fragment-linear bf16. Group g = (layer, ktile t, ctile c):
//   L0: g = t*8+c (128) | L1: 128 + t*8+c | L2: 256 + t*4+c (64)
// ws[((g*3+s)*64 + lane)*8 + i] = split_s( W[k=t*16+(lane>>5)*8+i][col=c*32+(lane&31)] )
__global__ void pack_w(const float* __restrict__ W0, const float* __restrict__ W1,
                       const float* __restrict__ W2, unsigned short* __restrict__ ws) {
    const int g = blockIdx.x;        // 0..319
    const int lane = threadIdx.x;    // 0..63
    const int hi = lane >> 5, ln31 = lane & 31;
    const float* W; int t, c, ldw, rowoff;
    if (g < 128)      { W = W0; t = g >> 3;        c = g & 7;        ldw = 256; rowoff = 1; }
    else if (g < 256) { W = W1; t = (g-128) >> 3;  c = (g-128) & 7;  ldw = 256; rowoff = 0; }
    else              { W = W2; t = (g-256) >> 2;  c = (g-256) & 3;  ldw = 128; rowoff = 0; }
    const int col = c * 32 + ln31;
    unsigned short hb[8], mb[8], lb[8];
    #pragma unroll
    for (int i = 0; i < 8; ++i) {
        const int k = t * 16 + hi * 8 + i;
        split3(W[(size_t)(rowoff + k) * ldw + col], hb[i], mb[i], lb[i]);
    }
    size_t base = ((size_t)(g * 3 + 0) * 64 + lane) * 8;
    #pragma unroll
    for (int i = 0; i < 8; ++i) ws[base + i] = hb[i];
    base += 64 * 8;
    #pragma unroll
    for (int i = 0; i < 8; ++i) ws[base + i] = mb[i];
    base += 64 * 8;
    #pragma unroll
    for (int i = 0; i < 8; ++i) ws[base + i] = lb[i];
}

// ---------------- fused main kernel ----------------
// mfma_f32_32x32x16_bf16: A[row=lane&31][k=(lane>>5)*8+i], B[k][col=lane&31],
// D: col=lane&31, row=(reg&3)+8*(reg>>2)+4*(lane>>5)  (verified in round 2).
template<int NC_TOT>
__device__ __forceinline__ void gemm_layer(const short8* __restrict__ wsL, const char* smem,
                                           f32x16& acc, int ctile, int row, int lane) {
    const int hi = lane >> 5;
    const int abase = row * 512;
    const int swzm = (row & 7) << 4;
    const short8* bp = wsL + (size_t)ctile * 192 + lane;
    #pragma unroll 2
    for (int t = 0; t < 16; ++t) {
        const int koff = abase + ((t * 32 + hi * 16) ^ swzm);
        short8 ah = *(const short8*)(smem + 0 * PLANE + koff);
        short8 am = *(const short8*)(smem + 1 * PLANE + koff);
        short8 al = *(const short8*)(smem + 2 * PLANE + koff);
        short8 bh = bp[0];
        short8 bm = bp[64];
        short8 bl = bp[128];
        bp += NC_TOT * 192;
        acc = __builtin_amdgcn_mfma_f32_32x32x16_bf16(ah, bh, acc, 0, 0, 0);
        acc = __builtin_amdgcn_mfma_f32_32x32x16_bf16(ah, bm, acc, 0, 0, 0);
        acc = __builtin_amdgcn_mfma_f32_32x32x16_bf16(am, bh, acc, 0, 0, 0);
        acc = __builtin_amdgcn_mfma_f32_32x32x16_bf16(ah, bl, acc, 0, 0, 0);
        acc = __builtin_amdgcn_mfma_f32_32x32x16_bf16(am, bm, acc, 0, 0, 0);
        acc = __builtin_amdgcn_mfma_f32_32x32x16_bf16(al, bh, acc, 0, 0, 0);
    }
}

// activation + re-split + write back into the LDS planes (they become next layer's A)
__device__ __forceinline__ void act_store_lds(const f32x16& acc, const int* __restrict__ act,
                                              char* smem, int wrbase, int ctile, int lane) {
    const int hi = lane >> 5, ln31 = lane & 31;
    const int col = ctile * 32 + ln31;
    const int aid = act[col];
    const int kbyte = 2 * col;
    __syncthreads();   // everyone done reading previous planes
    #pragma unroll
    for (int rr = 0; rr < 16; ++rr) {
        const float v = apply_act(aid, acc[rr]);
        const int row = wrbase + (rr & 3) + 8 * (rr >> 2) + 4 * hi;
        const int addr = row * 512 + (kbyte ^ ((row & 7) << 4));
        unsigned short h, m, l;
        split3(v, h, m, l);
        *(unsigned short*)(smem + 0 * PLANE + addr) = h;
        *(unsigned short*)(smem + 1 * PLANE + addr) = m;
        *(unsigned short*)(smem + 2 * PLANE + addr) = l;
    }
    __syncthreads();
}

__global__ __launch_bounds__(1024, 4)
void wann_mfma(const float* __restrict__ x,
               const float* __restrict__ W0,
               const unsigned short* __restrict__ ws,
               const int* __restrict__ a1, const int* __restrict__ a2,
               const int* __restrict__ a3,
               float* __restrict__ out) {
    extern __shared__ char smem[];           // 3 planes x 32 KiB
    const int tid = threadIdx.x;
    const int lane = tid & 63;
    const int wid = tid >> 6;                // 0..15
    const int ln31 = lane & 31;
    const int hi = lane >> 5;
    const int wc = wid & 7;                  // col tile (L1/L2)
    const int wr = wid >> 3;                 // row group (L1/L2)
    const int row = wr * 32 + ln31;          // A-fragment row
    const int row0 = blockIdx.x * TB;

    // ---- stage x: global float4 -> split3 -> LDS planes ----
    {
        const float4* xv = (const float4*)(x + (size_t)row0 * 256);
        #pragma unroll
        for (int p = 0; p < 4; ++p) {
            const int f = p * 1024 + tid;
            const int r = f >> 6;            // row 0..63
            const int swz = (r & 7) << 4;
            const int kb0 = (f & 63) * 8;    // byte offset of the 4 bf16 pairs
            const float4 v = xv[f];
            const float vv[4] = {v.x, v.y, v.z, v.w};
            #pragma unroll
            for (int e = 0; e < 4; ++e) {
                unsigned short h, m, l;
                split3(vv[e], h, m, l);
                const int addr = r * 512 + ((kb0 + 2 * e) ^ swz);
                *(unsigned short*)(smem + 0 * PLANE + addr) = h;
                *(unsigned short*)(smem + 1 * PLANE + addr) = m;
                *(unsigned short*)(smem + 2 * PLANE + addr) = l;
            }
        }
    }
    __syncthreads();

    const short8* wsv  = (const short8*)ws;
    const short8* wsL0 = wsv;
    const short8* wsL1 = wsv + (size_t)128 * 3 * 64;
    const short8* wsL2 = wsv + (size_t)256 * 3 * 64;

    f32x16 acc;

    // ---- layer 1 (bias = W0 row 0) ----
    {
        const float b = W0[wc * 32 + ln31];
        #pragma unroll
        for (int rr = 0; rr < 16; ++rr) acc[rr] = b;
        gemm_layer<8>(wsL0, smem, acc, wc, row, lane);
        act_store_lds(acc, a1, smem, wr * 32, wc, lane);
    }

    // ---- layer 2 ----
    {
        #pragma unroll
        for (int rr = 0; rr < 16; ++rr) acc[rr] = 0.0f;
        gemm_layer<8>(wsL1, smem, acc, wc, row, lane);
        act_store_lds(acc, a2, smem, wr * 32, wc, lane);
    }

    // ---- layer 3: 128 cols -> 8 active waves, direct store ----
    if (wid < 8) {
        const int wc3 = wid & 3, wr3 = wid >> 2;
        const int row3 = wr3 * 32 + ln31;
        #pragma unroll
        for (int rr = 0; rr < 16; ++rr) acc[rr] = 0.0f;
        gemm_layer<4>(wsL2, smem, acc, wc3, row3, lane);
        const int col = wc3 * 32 + ln31;
        const int aid = a3[col];
        #pragma unroll
        for (int rr = 0; rr < 16; ++rr) {
            const float v = apply_act(aid, acc[rr]);
            const int orow = wr3 * 32 + (rr & 3) + 8 * (rr >> 2) + 4 * hi;
            out[(size_t)(row0 + orow) * 128 + col] = v;
        }
    }
}

extern "C" void kernel_launch(void* const* d_in, const int* in_sizes, int n_in,
                              void* d_out, int out_size, void* d_ws, size_t ws_size,
                              hipStream_t stream) {
    const float* x  = (const float*)d_in[0];
    const float* W0 = (const float*)d_in[1];   // [257,256], row 0 = bias
    const float* W1 = (const float*)d_in[2];   // [256,256]
    const float* W2 = (const float*)d_in[3];   // [256,128]
    const int*   a1 = (const int*)d_in[4];
    const int*   a2 = (const int*)d_in[5];
    const int*   a3 = (const int*)d_in[6];
    float* out = (float*)d_out;

    unsigned short* ws = (unsigned short*)d_ws;   // 983040 B packed bf16 fragments

    hipFuncSetAttribute(reinterpret_cast<const void*>(wann_mfma),
                        hipFuncAttributeMaxDynamicSharedMemorySize, 3 * PLANE);

    hipLaunchKernelGGL(pack_w, dim3(320), dim3(64), 0, stream, W0, W1, W2, ws);

    const int B = in_sizes[0] / 256;           // 65536
    hipLaunchKernelGGL(wann_mfma, dim3(B / TB), dim3(1024), 3 * PLANE, stream,
                       x, W0, ws, a1, a2, a3, out);
}

// Round 4
// 227.291 us; speedup vs baseline: 3.0708x; 1.1156x over previous
//
#include <hip/hip_runtime.h>
#include <hip/hip_bf16.h>
#include <math.h>

typedef __attribute__((ext_vector_type(8)))  short short8;   // 8 bf16 (4 VGPRs) MFMA operand
typedef __attribute__((ext_vector_type(16))) float f32x16;   // 32x32 MFMA accumulator

constexpr int TB = 32;          // batch rows per block
constexpr int PLANE = 16384;    // one LDS split-plane: 32 rows * 256 k * 2B, row stride 512B
// XOR swizzle (row&7)<<4 spreads the stride-512B column accesses across 8 16B slots.

__device__ __forceinline__ float vexp2f(float x) {   // 2^x
    float r; asm("v_exp_f32 %0, %1" : "=v"(r) : "v"(x)); return r;
}

__device__ __forceinline__ unsigned int bf16_rne_bits(float x) {
    unsigned int u = __float_as_uint(x);
    return (u + 0x7fffu + ((u >> 16) & 1u)) & 0xffff0000u;
}
// 3-term split: x = h + m + l + O(2^-24 |x|)   (l truncated)
__device__ __forceinline__ void split3(float x, unsigned short& h, unsigned short& m, unsigned short& l) {
    const unsigned int hb = bf16_rne_bits(x);
    const float r1 = x - __uint_as_float(hb);
    const unsigned int mb = bf16_rne_bits(r1);
    const float r2 = r1 - __uint_as_float(mb);
    h = (unsigned short)(hb >> 16);
    m = (unsigned short)(mb >> 16);
    l = (unsigned short)(__float_as_uint(r2) >> 16);
}

// Branchless per-node activation: 3 transcendentals total (v_sin, v_exp, v_rcp).
// sin(pi*x)=sin2pi(fract(x/2)); cos(pi*x)=sin2pi(fract(x/2+1/4));
// gauss=2^(-x^2*log2e/2); tanh=1-2/(2^(2x*log2e)+1); sigmoid=1/(1+2^(-x*log2e)).
__device__ __forceinline__ float apply_act(int a, float x) {
    const float x2 = x * x;
    const float roff = (a == 10) ? 0.25f : 0.0f;
    const float r  = __builtin_amdgcn_fractf(fmaf(0.5f, x, roff));
    const float sn = __builtin_amdgcn_sinf(r);
    const float eop = (a == 4) ? x2 : x;
    const float ecf = (a == 4) ? -0.72134752044448169f
                               : ((a == 5) ? 2.8853900817779268f : -1.4426950408889634f);
    const float e  = vexp2f(eop * ecf);
    const float d  = __builtin_amdgcn_rcpf(1.0f + e);
    float ev = d;                                   // id 6: sigmoid
    ev = (a == 4) ? e : ev;                         // id 4: gauss
    ev = (a == 5) ? fmaf(-2.0f, d, 1.0f) : ev;      // id 5: tanh
    float v = x;
    v = (a == 2)  ? (x > 0.0f ? 1.0f : 0.0f) : v;
    v = (a == 3 || a == 10) ? sn : v;
    v = (a >= 4 && a <= 6)  ? ev : v;
    v = (a == 7)  ? -x : v;
    v = (a == 8)  ? fabsf(x) : v;
    v = (a == 9)  ? fmaxf(0.0f, x) : v;
    v = (a == 11) ? x2 : v;
    return v;
}

// ---------------- weight pre-pack (layout unchanged since round 2) ----------------
// ws: fragment-linear bf16. Group g = (layer, ktile t, ctile c):
//   L0: g = t*8+c (128) | L1: 128 + t*8+c | L2: 256 + t*4+c (64)
// ws[((g*3+s)*64 + lane)*8 + i] = split_s( W[k=t*16+(lane>>5)*8+i][col=c*32+(lane&31)] )
__global__ void pack_w(const float* __restrict__ W0, const float* __restrict__ W1,
                       const float* __restrict__ W2, unsigned short* __restrict__ ws) {
    const int g = blockIdx.x;        // 0..319
    const int lane = threadIdx.x;    // 0..63
    const int hi = lane >> 5, ln31 = lane & 31;
    const float* W; int t, c, ldw, rowoff;
    if (g < 128)      { W = W0; t = g >> 3;        c = g & 7;        ldw = 256; rowoff = 1; }
    else if (g < 256) { W = W1; t = (g-128) >> 3;  c = (g-128) & 7;  ldw = 256; rowoff = 0; }
    else              { W = W2; t = (g-256) >> 2;  c = (g-256) & 3;  ldw = 128; rowoff = 0; }
    const int col = c * 32 + ln31;
    unsigned short hb[8], mb[8], lb[8];
    #pragma unroll
    for (int i = 0; i < 8; ++i) {
        const int k = t * 16 + hi * 8 + i;
        split3(W[(size_t)(rowoff + k) * ldw + col], hb[i], mb[i], lb[i]);
    }
    size_t base = ((size_t)(g * 3 + 0) * 64 + lane) * 8;
    #pragma unroll
    for (int i = 0; i < 8; ++i) ws[base + i] = hb[i];
    base += 64 * 8;
    #pragma unroll
    for (int i = 0; i < 8; ++i) ws[base + i] = mb[i];
    base += 64 * 8;
    #pragma unroll
    for (int i = 0; i < 8; ++i) ws[base + i] = lb[i];
}

// ---------------- fused main kernel ----------------
// mfma_f32_32x32x16_bf16: A[row=lane&31][k=(lane>>5)*8+i], B[k][col=lane&31],
// D: col=lane&31, row=(reg&3)+8*(reg>>2)+4*(lane>>5)  (HW-verified rounds 2-3).
template<int NC_TOT>
__device__ __forceinline__ void gemm_layer(const short8* __restrict__ wsL, const char* smem,
                                           f32x16& acc, int ctile, int lane) {
    const int hi = lane >> 5, ln31 = lane & 31;
    const int abase = ln31 * 512;
    const int swzm = (ln31 & 7) << 4;
    const short8* bp = wsL + (size_t)ctile * 192 + lane;
    #pragma unroll 2
    for (int t = 0; t < 16; ++t) {
        const int koff = abase + ((t * 32 + hi * 16) ^ swzm);
        short8 ah = *(const short8*)(smem + 0 * PLANE + koff);
        short8 am = *(const short8*)(smem + 1 * PLANE + koff);
        short8 al = *(const short8*)(smem + 2 * PLANE + koff);
        short8 bh = bp[0];
        short8 bm = bp[64];
        short8 bl = bp[128];
        bp += NC_TOT * 192;
        acc = __builtin_amdgcn_mfma_f32_32x32x16_bf16(ah, bh, acc, 0, 0, 0);
        acc = __builtin_amdgcn_mfma_f32_32x32x16_bf16(ah, bm, acc, 0, 0, 0);
        acc = __builtin_amdgcn_mfma_f32_32x32x16_bf16(am, bh, acc, 0, 0, 0);
        acc = __builtin_amdgcn_mfma_f32_32x32x16_bf16(ah, bl, acc, 0, 0, 0);
        acc = __builtin_amdgcn_mfma_f32_32x32x16_bf16(am, bm, acc, 0, 0, 0);
        acc = __builtin_amdgcn_mfma_f32_32x32x16_bf16(al, bh, acc, 0, 0, 0);
    }
}

// activation + re-split + write back into the LDS planes (next layer's A)
__device__ __forceinline__ void act_store_lds(const f32x16& acc, const int* __restrict__ act,
                                              char* smem, int ctile, int lane) {
    const int hi = lane >> 5, ln31 = lane & 31;
    const int col = ctile * 32 + ln31;
    const int aid = act[col];
    const int kbyte = 2 * col;
    __syncthreads();   // everyone done reading previous planes
    #pragma unroll
    for (int rr = 0; rr < 16; ++rr) {
        const float v = apply_act(aid, acc[rr]);
        const int row = (rr & 3) + 8 * (rr >> 2) + 4 * hi;      // 0..31
        const int addr = row * 512 + (kbyte ^ ((row & 7) << 4));
        unsigned short h, m, l;
        split3(v, h, m, l);
        *(unsigned short*)(smem + 0 * PLANE + addr) = h;
        *(unsigned short*)(smem + 1 * PLANE + addr) = m;
        *(unsigned short*)(smem + 2 * PLANE + addr) = l;
    }
    __syncthreads();
}

__global__ __launch_bounds__(512, 6)
void wann_mfma(const float* __restrict__ x,
               const float* __restrict__ W0,
               const unsigned short* __restrict__ ws,
               const int* __restrict__ a1, const int* __restrict__ a2,
               const int* __restrict__ a3,
               float* __restrict__ out) {
    extern __shared__ char smem[];           // 3 planes x 16 KiB
    const int tid = threadIdx.x;
    const int lane = tid & 63;
    const int wid = tid >> 6;                // 0..7 = ctile
    const int ln31 = lane & 31;
    const int hi = lane >> 5;
    const int row0 = blockIdx.x * TB;

    // ---- stage x[row0:row0+32, :]: global float4 -> split3 -> LDS planes ----
    {
        const float4* xv = (const float4*)(x + (size_t)row0 * 256);
        #pragma unroll
        for (int p = 0; p < 4; ++p) {
            const int f = p * 512 + tid;     // 0..2047
            const int r = f >> 6;            // row 0..31
            const int swz = (r & 7) << 4;
            const int kb0 = (f & 63) * 8;    // byte offset of the 4 bf16 pairs
            const float4 v = xv[f];
            const float vv[4] = {v.x, v.y, v.z, v.w};
            #pragma unroll
            for (int e = 0; e < 4; ++e) {
                unsigned short h, m, l;
                split3(vv[e], h, m, l);
                const int addr = r * 512 + ((kb0 + 2 * e) ^ swz);
                *(unsigned short*)(smem + 0 * PLANE + addr) = h;
                *(unsigned short*)(smem + 1 * PLANE + addr) = m;
                *(unsigned short*)(smem + 2 * PLANE + addr) = l;
            }
        }
    }
    __syncthreads();

    const short8* wsv  = (const short8*)ws;
    const short8* wsL0 = wsv;
    const short8* wsL1 = wsv + (size_t)128 * 3 * 64;
    const short8* wsL2 = wsv + (size_t)256 * 3 * 64;

    f32x16 acc;

    // ---- layer 1 (bias = W0 row 0), ctile = wid ----
    {
        const float b = W0[wid * 32 + ln31];
        #pragma unroll
        for (int rr = 0; rr < 16; ++rr) acc[rr] = b;
        gemm_layer<8>(wsL0, smem, acc, wid, lane);
        act_store_lds(acc, a1, smem, wid, lane);
    }

    // ---- layer 2 ----
    {
        #pragma unroll
        for (int rr = 0; rr < 16; ++rr) acc[rr] = 0.0f;
        gemm_layer<8>(wsL1, smem, acc, wid, lane);
        act_store_lds(acc, a2, smem, wid, lane);
    }

    // ---- layer 3: 128 cols -> waves 0..3, direct store ----
    if (wid < 4) {
        #pragma unroll
        for (int rr = 0; rr < 16; ++rr) acc[rr] = 0.0f;
        gemm_layer<4>(wsL2, smem, acc, wid, lane);
        const int col = wid * 32 + ln31;
        const int aid = a3[col];
        #pragma unroll
        for (int rr = 0; rr < 16; ++rr) {
            const float v = apply_act(aid, acc[rr]);
            const int orow = (rr & 3) + 8 * (rr >> 2) + 4 * hi;
            out[(size_t)(row0 + orow) * 128 + col] = v;
        }
    }
}

extern "C" void kernel_launch(void* const* d_in, const int* in_sizes, int n_in,
                              void* d_out, int out_size, void* d_ws, size_t ws_size,
                              hipStream_t stream) {
    const float* x  = (const float*)d_in[0];
    const float* W0 = (const float*)d_in[1];   // [257,256], row 0 = bias
    const float* W1 = (const float*)d_in[2];   // [256,256]
    const float* W2 = (const float*)d_in[3];   // [256,128]
    const int*   a1 = (const int*)d_in[4];
    const int*   a2 = (const int*)d_in[5];
    const int*   a3 = (const int*)d_in[6];
    float* out = (float*)d_out;

    unsigned short* ws = (unsigned short*)d_ws;   // 983040 B packed bf16 fragments

    hipFuncSetAttribute(reinterpret_cast<const void*>(wann_mfma),
                        hipFuncAttributeMaxDynamicSharedMemorySize, 3 * PLANE);

    hipLaunchKernelGGL(pack_w, dim3(320), dim3(64), 0, stream, W0, W1, W2, ws);

    const int B = in_sizes[0] / 256;           // 65536
    hipLaunchKernelGGL(wann_mfma, dim3(B / TB), dim3(512), 3 * PLANE, stream,
                       x, W0, ws, a1, a2, a3, out);
}